// Round 13
// baseline (588.329 us; speedup 1.0000x reference)
//
#include <hip/hip_runtime.h>
#include <cstdint>
#include <cstddef>

#define N_NODES 100000
#define N_EDGES 1600000
#define HID 128
#define SCAN_BLOCKS ((N_NODES + 255) / 256)   // 391

using frag_ab = __attribute__((ext_vector_type(8))) short;  // 8 bf16 (4 VGPRs)
using f32x4   = __attribute__((ext_vector_type(4))) float;  // MFMA accumulator

__device__ __forceinline__ unsigned short f2bf(float f) {   // RNE f32->bf16
    uint32_t u = __builtin_bit_cast(uint32_t, f);
    u += 0x7fffu + ((u >> 16) & 1u);
    return (unsigned short)(u >> 16);
}
__device__ __forceinline__ float bf2f(unsigned short u) {
    uint32_t v = (uint32_t)u << 16;
    return __builtin_bit_cast(float, v);
}

// ---------------------------------------------------------------- deg histogram
__global__ __launch_bounds__(256) void k_count(const int* __restrict__ col,
                                               int* __restrict__ deg) {
    int e = blockIdx.x * 256 + threadIdx.x;
    if (e < N_EDGES) atomicAdd(&deg[col[e]], 1);
}

__global__ __launch_bounds__(256) void k_dinv(const int* __restrict__ deg,
                                              float* __restrict__ dinv) {
    int i = blockIdx.x * 256 + threadIdx.x;
    if (i < N_NODES) dinv[i] = rsqrtf((float)deg[i] + 1.0f);  // +1 self-loop
}

// ---------------------------------------------------------------- exclusive scan
__global__ __launch_bounds__(256) void k_scan1(const int* __restrict__ deg,
                                               int* __restrict__ cursor,
                                               int* __restrict__ bsum) {
    __shared__ int s[256];
    const int t = threadIdx.x;
    const int i = blockIdx.x * 256 + t;
    int v = (i < N_NODES) ? deg[i] : 0;
    s[t] = v;
    __syncthreads();
#pragma unroll
    for (int d = 1; d < 256; d <<= 1) {
        int a = (t >= d) ? s[t - d] : 0;
        __syncthreads();
        s[t] += a;
        __syncthreads();
    }
    if (i < N_NODES) cursor[i] = s[t] - v;
    if (t == 255) bsum[blockIdx.x] = s[t];
}

__global__ __launch_bounds__(512) void k_scan2(int* __restrict__ bsum, int n) {
    __shared__ int s[512];
    const int t = threadIdx.x;
    int v = (t < n) ? bsum[t] : 0;
    s[t] = v;
    __syncthreads();
#pragma unroll
    for (int d = 1; d < 512; d <<= 1) {
        int a = (t >= d) ? s[t - d] : 0;
        __syncthreads();
        s[t] += a;
        __syncthreads();
    }
    if (t < n) bsum[t] = s[t] - v;
}

__global__ __launch_bounds__(256) void k_scan3(int* __restrict__ cursor,
                                               const int* __restrict__ bsum) {
    const int i = blockIdx.x * 256 + threadIdx.x;
    if (i < N_NODES) cursor[i] += bsum[blockIdx.x];
}

// ---------------------------------------------------------------- CSR placement
// Payload is ONLY srow (norm is folded into xws rows). After this kernel
// cursor[c] = end of segment c.
__global__ __launch_bounds__(256) void k_place(const int* __restrict__ row,
                                               const int* __restrict__ col,
                                               int* __restrict__ cursor,
                                               int* __restrict__ srow) {
    const int e = blockIdx.x * 256 + threadIdx.x;
    if (e >= N_EDGES) return;
    const int r = row[e];
    const int c = col[e];
    const int p = atomicAdd(&cursor[c], 1);
    srow[p] = r;
}

// ---------------------------------------------------------------- W -> Wt (bf16, transposed)
template <int K>
__global__ __launch_bounds__(256) void k_wt(const float* __restrict__ W,
                                            short* __restrict__ Wt) {
    const int idx = blockIdx.x * 256 + threadIdx.x;
    if (idx >= K * HID) return;
    const int k = idx >> 7;          // / 128
    const int n = idx & 127;
    Wt[n * K + k] = (short)f2bf(W[idx]);
}

// ---------------------------------------------------------------- bf16 MFMA GEMM (A = f32)
// C[M,128](bf16) = dinv[m] * (A[M,K](f32) @ Wt[n][k](bf16))   (row-prescaled!)
// mfma_f32_16x16x32_bf16 layouts (learn_hip m89): A: row=l&15, k=(l>>4)*8+j;
// B: k=(l>>4)*8+j, col=l&15; C/D: col=l&15, row=(l>>4)*4+reg.
template <int K>
__global__ __launch_bounds__(256) void k_mfma_f32A(const float* __restrict__ A,
                                                   const short* __restrict__ Wt,
                                                   const float* __restrict__ dinv,
                                                   unsigned short* __restrict__ C) {
    const int tid  = threadIdx.x;
    const int w    = tid >> 6;
    const int lane = tid & 63;
    const int l15  = lane & 15;
    const int kg   = lane >> 4;
    const int m0   = blockIdx.x * 128;

    f32x4 acc[2][8];
#pragma unroll
    for (int rb = 0; rb < 2; ++rb)
#pragma unroll
        for (int c = 0; c < 8; ++c)
            acc[rb][c] = (f32x4){0.f, 0.f, 0.f, 0.f};

    for (int k0 = 0; k0 < K; k0 += 32) {
        frag_ab afr[2];
#pragma unroll
        for (int rb = 0; rb < 2; ++rb) {
            int ar = m0 + w * 16 + rb * 64 + l15;
            if (ar >= N_NODES) ar = N_NODES - 1;     // tail clamp (store predicated)
            const float4* ap =
                reinterpret_cast<const float4*>(A + (size_t)ar * K + k0 + kg * 8);
            const float4 v0 = ap[0];
            const float4 v1 = ap[1];
            afr[rb][0] = (short)f2bf(v0.x); afr[rb][1] = (short)f2bf(v0.y);
            afr[rb][2] = (short)f2bf(v0.z); afr[rb][3] = (short)f2bf(v0.w);
            afr[rb][4] = (short)f2bf(v1.x); afr[rb][5] = (short)f2bf(v1.y);
            afr[rb][6] = (short)f2bf(v1.z); afr[rb][7] = (short)f2bf(v1.w);
        }
#pragma unroll
        for (int c = 0; c < 8; ++c) {
            const frag_ab bfr = *reinterpret_cast<const frag_ab*>(
                Wt + (size_t)(c * 16 + l15) * K + k0 + kg * 8);
            acc[0][c] = __builtin_amdgcn_mfma_f32_16x16x32_bf16(afr[0], bfr, acc[0][c], 0, 0, 0);
            acc[1][c] = __builtin_amdgcn_mfma_f32_16x16x32_bf16(afr[1], bfr, acc[1][c], 0, 0, 0);
        }
    }
#pragma unroll
    for (int rb = 0; rb < 2; ++rb) {
        const int rbase = m0 + w * 16 + rb * 64 + kg * 4;
        float dv[4];
#pragma unroll
        for (int i = 0; i < 4; ++i)
            dv[i] = (rbase + i < N_NODES) ? dinv[rbase + i] : 0.f;  // wave-broadcast, L2-hot
#pragma unroll
        for (int c = 0; c < 8; ++c)
#pragma unroll
            for (int i = 0; i < 4; ++i) {
                const int rr = rbase + i;
                if (rr < N_NODES)
                    C[(size_t)rr * HID + c * 16 + l15] = f2bf(dv[i] * acc[rb][c][i]);
            }
    }
}

// ---------------------------------------------------------------- bf16 MFMA GEMM (A = bf16)
template <int K>
__global__ __launch_bounds__(256) void k_mfma_bf16A(const unsigned short* __restrict__ A,
                                                    const short* __restrict__ Wt,
                                                    const float* __restrict__ dinv,
                                                    unsigned short* __restrict__ C) {
    const int tid  = threadIdx.x;
    const int w    = tid >> 6;
    const int lane = tid & 63;
    const int l15  = lane & 15;
    const int kg   = lane >> 4;
    const int m0   = blockIdx.x * 128;

    f32x4 acc[2][8];
#pragma unroll
    for (int rb = 0; rb < 2; ++rb)
#pragma unroll
        for (int c = 0; c < 8; ++c)
            acc[rb][c] = (f32x4){0.f, 0.f, 0.f, 0.f};

    for (int k0 = 0; k0 < K; k0 += 32) {
        frag_ab afr[2];
#pragma unroll
        for (int rb = 0; rb < 2; ++rb) {
            int ar = m0 + w * 16 + rb * 64 + l15;
            if (ar >= N_NODES) ar = N_NODES - 1;
            afr[rb] = *reinterpret_cast<const frag_ab*>(A + (size_t)ar * K + k0 + kg * 8);
        }
#pragma unroll
        for (int c = 0; c < 8; ++c) {
            const frag_ab bfr = *reinterpret_cast<const frag_ab*>(
                Wt + (size_t)(c * 16 + l15) * K + k0 + kg * 8);
            acc[0][c] = __builtin_amdgcn_mfma_f32_16x16x32_bf16(afr[0], bfr, acc[0][c], 0, 0, 0);
            acc[1][c] = __builtin_amdgcn_mfma_f32_16x16x32_bf16(afr[1], bfr, acc[1][c], 0, 0, 0);
        }
    }
#pragma unroll
    for (int rb = 0; rb < 2; ++rb) {
        const int rbase = m0 + w * 16 + rb * 64 + kg * 4;
        float dv[4];
#pragma unroll
        for (int i = 0; i < 4; ++i)
            dv[i] = (rbase + i < N_NODES) ? dinv[rbase + i] : 0.f;
#pragma unroll
        for (int c = 0; c < 8; ++c)
#pragma unroll
            for (int i = 0; i < 4; ++i) {
                const int rr = rbase + i;
                if (rr < N_NODES)
                    C[(size_t)rr * HID + c * 16 + l15] = f2bf(dv[i] * acc[rb][c][i]);
            }
    }
}

// ---------------------------------------------------------------- gather + epilogue
// xws rows are pre-scaled by dinv:   out[c] = tanh( dc*(Σ_j xws[srow[j]] + xws[c]) + b )
// No per-edge weights at all. f32 accumulate. OUT_BF16 selects h1(bf16) vs final(f32).
template <bool OUT_BF16>
__global__ __launch_bounds__(256) void k_gather_act(const unsigned short* __restrict__ xws,
                                                    const int* __restrict__ srow,
                                                    const int* __restrict__ cursor,
                                                    const float* __restrict__ dinv,
                                                    const float* __restrict__ b,
                                                    void* __restrict__ outv) {
    const int tid = threadIdx.x;
    const int node = blockIdx.x * 8 + (tid >> 5);
    if (node >= N_NODES) return;
    const int ch = (tid & 31) * 4;               // 4 bf16 per lane (8 B)

    const int start = (node == 0) ? 0 : cursor[node - 1];
    const int end = cursor[node];

    float4 acc = make_float4(0.f, 0.f, 0.f, 0.f);
#pragma unroll 2
    for (int j = start; j < end; ++j) {
        const int r = srow[j];
        const ushort4 v = *reinterpret_cast<const ushort4*>(xws + (size_t)r * HID + ch);
        acc.x += bf2f(v.x);
        acc.y += bf2f(v.y);
        acc.z += bf2f(v.z);
        acc.w += bf2f(v.w);
    }

    const float dc = dinv[node];
    const ushort4 xv = *reinterpret_cast<const ushort4*>(xws + (size_t)node * HID + ch);
    const float4 bv = *reinterpret_cast<const float4*>(b + ch);
    float o0 = tanhf(dc * (acc.x + bf2f(xv.x)) + bv.x);
    float o1 = tanhf(dc * (acc.y + bf2f(xv.y)) + bv.y);
    float o2 = tanhf(dc * (acc.z + bf2f(xv.z)) + bv.z);
    float o3 = tanhf(dc * (acc.w + bf2f(xv.w)) + bv.w);

    if (OUT_BF16) {
        ushort4 o = {f2bf(o0), f2bf(o1), f2bf(o2), f2bf(o3)};
        *reinterpret_cast<ushort4*>((unsigned short*)outv + (size_t)node * HID + ch) = o;
    } else {
        *reinterpret_cast<float4*>((float*)outv + (size_t)node * HID + ch) =
            make_float4(o0, o1, o2, o3);
    }
}

// ---------------------------------------------------------------- launch
extern "C" void kernel_launch(void* const* d_in, const int* in_sizes, int n_in,
                              void* d_out, int out_size, void* d_ws, size_t ws_size,
                              hipStream_t stream) {
    const float* x  = (const float*)d_in[0];
    const int*   ei = (const int*)d_in[1];
    const int*   row = ei;                       // edge_index[0]
    const int*   col = ei + N_EDGES;             // edge_index[1]
    const float* W1 = (const float*)d_in[2];
    const float* b1 = (const float*)d_in[3];
    const float* W2 = (const float*)d_in[4];
    const float* b2 = (const float*)d_in[5];
    float* out = (float*)d_out;

    // workspace (~59 MB): xwb | h1b | dinv | deg | cursor | bsum | srow | wt1 | wt2
    unsigned short* xwb = (unsigned short*)d_ws;                   // [N,128] bf16 (dinv-scaled)
    unsigned short* h1b = xwb + (size_t)N_NODES * HID;             // [N,128] bf16
    float* dinv   = (float*)(h1b + (size_t)N_NODES * HID);
    int*   deg    = (int*)(dinv + N_NODES);
    int*   cursor = deg + N_NODES;
    int*   bsum   = cursor + N_NODES;
    int*   srow   = bsum + 512;
    short* wt1    = (short*)(srow + N_EDGES);                      // [128][256] bf16
    short* wt2    = wt1 + 128 * 256;                               // [128][128] bf16

    // ---- weight transpose+convert (tiny)
    k_wt<256><<<(256 * HID + 255) / 256, 256, 0, stream>>>(W1, wt1);
    k_wt<128><<<(128 * HID + 255) / 256, 256, 0, stream>>>(W2, wt2);

    // ---- CSR build (shared by both layers)
    hipMemsetAsync(deg, 0, N_NODES * sizeof(int), stream);
    k_count<<<(N_EDGES + 255) / 256, 256, 0, stream>>>(col, deg);
    k_dinv<<<(N_NODES + 255) / 256, 256, 0, stream>>>(deg, dinv);
    k_scan1<<<SCAN_BLOCKS, 256, 0, stream>>>(deg, cursor, bsum);
    k_scan2<<<1, 512, 0, stream>>>(bsum, SCAN_BLOCKS);
    k_scan3<<<SCAN_BLOCKS, 256, 0, stream>>>(cursor, bsum);
    k_place<<<(N_EDGES + 255) / 256, 256, 0, stream>>>(row, col, cursor, srow);

    // ---- layer 1: h1b = bf16(tanh(dc*(agg+self) + b1)), xwb = dinv ⊙ (x@W1)
    k_mfma_f32A<256><<<(N_NODES + 127) / 128, 256, 0, stream>>>(x, wt1, dinv, xwb);
    k_gather_act<true><<<N_NODES / 8, 256, 0, stream>>>(xwb, srow, cursor, dinv, b1, h1b);

    // ---- layer 2: out = tanh(dc*(agg+self) + b2), xwb = dinv ⊙ (h1b@W2)
    k_mfma_bf16A<128><<<(N_NODES + 127) / 128, 256, 0, stream>>>(h1b, wt2, dinv, xwb);
    k_gather_act<false><<<N_NODES / 8, 256, 0, stream>>>(xwb, srow, cursor, dinv, b2, out);
}